// Round 4
// baseline (616.174 us; speedup 1.0000x reference)
//
#include <hip/hip_runtime.h>
#include <math.h>

// Node2GraphAttention: out[g] = sum_{i: batch[i]==g} sigmoid(<n_i, g_emb[g]>) * n_i
// N=500000, D=128, G=10000, n_batch sorted ascending.
//
// R4: OCTET decomposition. 8 lanes per node; lane (l&7) owns 16 contiguous
// cols (4x float4) -> full 512B row per octet, coalesced. Dot reduction is
// only 3 __shfl_xor steps (masks 1,2,4 stay inside the octet) vs 5 for the
// 32-lane layout: 6.7x fewer ds_swizzle ops, shallower dependent chain.
// Manual 1-group lookahead keeps 8KB/wave of loads in flight across the
// boundary branches (R3 was burst-idle -> ~2.5 TB/s effective).
// 32768 octets x per=16: 500000 = 31250*16 exactly -> no tails.
// Sorted batch => register g-row cache + register acc, atomic flush on
// graph-id change only.

#define BLOCK_THREADS 256
#define GRID_BLOCKS   1024
#define U 2                      // nodes per pipeline stage

__device__ __forceinline__ float dot16(const float4 a[4], const float4 b[4]) {
    float s = 0.f;
    #pragma unroll
    for (int t = 0; t < 4; ++t)
        s += a[t].x * b[t].x + a[t].y * b[t].y + a[t].z * b[t].z + a[t].w * b[t].w;
    return s;
}

__global__ __launch_bounds__(BLOCK_THREADS)
void n2g_attention_kernel(const float* __restrict__ n_emb,
                          const float* __restrict__ g_emb,
                          const int*   __restrict__ n_batch,
                          float* __restrict__ out,
                          int N)
{
    const int octet_id = blockIdx.x * (BLOCK_THREADS >> 3) + (threadIdx.x >> 3);
    const int lane8    = threadIdx.x & 7;
    const int col      = lane8 * 16;            // this lane's 16 columns
    const int num_oct  = GRID_BLOCKS * (BLOCK_THREADS >> 3);

    int per = (N + num_oct - 1) / num_oct;
    per = (per + U - 1) & ~(U - 1);
    const int start = octet_id * per;
    if (start >= N) return;
    const int end = min(start + per, N);

    float4 acc[4] = {make_float4(0,0,0,0), make_float4(0,0,0,0),
                     make_float4(0,0,0,0), make_float4(0,0,0,0)};

    int cur_g = n_batch[start];
    float4 gv[4];
    #pragma unroll
    for (int t = 0; t < 4; ++t)
        gv[t] = *(const float4*)(g_emb + (size_t)cur_g * 128 + col + 4 * t);

    // ---- prefetch stage 0 ----
    int    b_n[U];
    float4 nv_n[U][4];
    {
        #pragma unroll
        for (int j = 0; j < U; ++j) b_n[j] = n_batch[start + j];
        #pragma unroll
        for (int j = 0; j < U; ++j)
            #pragma unroll
            for (int t = 0; t < 4; ++t)
                nv_n[j][t] = *(const float4*)(n_emb + (size_t)(start + j) * 128 + col + 4 * t);
    }

    int i = start;
    for (; i + U <= end; i += U) {
        // consume prefetched
        int    b[U];
        float4 nv[U][4];
        #pragma unroll
        for (int j = 0; j < U; ++j) {
            b[j] = b_n[j];
            #pragma unroll
            for (int t = 0; t < 4; ++t) nv[j][t] = nv_n[j][t];
        }

        // issue next stage's loads before any compute
        const int inext = i + U;
        if (inext + U <= end) {
            #pragma unroll
            for (int j = 0; j < U; ++j) b_n[j] = n_batch[inext + j];
            #pragma unroll
            for (int j = 0; j < U; ++j)
                #pragma unroll
                for (int t = 0; t < 4; ++t)
                    nv_n[j][t] = *(const float4*)(n_emb + (size_t)(inext + j) * 128 + col + 4 * t);
        }

        // compute the U nodes
        #pragma unroll
        for (int j = 0; j < U; ++j) {
            if (b[j] != cur_g) {
                #pragma unroll
                for (int t = 0; t < 4; ++t) {
                    atomicAdd(&out[(size_t)cur_g * 128 + col + 4 * t + 0], acc[t].x);
                    atomicAdd(&out[(size_t)cur_g * 128 + col + 4 * t + 1], acc[t].y);
                    atomicAdd(&out[(size_t)cur_g * 128 + col + 4 * t + 2], acc[t].z);
                    atomicAdd(&out[(size_t)cur_g * 128 + col + 4 * t + 3], acc[t].w);
                    acc[t] = make_float4(0, 0, 0, 0);
                }
                cur_g = b[j];
                #pragma unroll
                for (int t = 0; t < 4; ++t)
                    gv[t] = *(const float4*)(g_emb + (size_t)cur_g * 128 + col + 4 * t);
            }
            float d = dot16(nv[j], gv);
            d += __shfl_xor(d, 1, 64);
            d += __shfl_xor(d, 2, 64);
            d += __shfl_xor(d, 4, 64);
            const float c = 1.0f / (1.0f + __expf(-d));
            #pragma unroll
            for (int t = 0; t < 4; ++t) {
                acc[t].x += c * nv[j][t].x;
                acc[t].y += c * nv[j][t].y;
                acc[t].z += c * nv[j][t].z;
                acc[t].w += c * nv[j][t].w;
            }
        }
    }

    // safety tail (unused for N=500000: 31250*16 exact)
    for (; i < end; ++i) {
        const int g = n_batch[i];
        float4 nv[4];
        #pragma unroll
        for (int t = 0; t < 4; ++t)
            nv[t] = *(const float4*)(n_emb + (size_t)i * 128 + col + 4 * t);
        if (g != cur_g) {
            #pragma unroll
            for (int t = 0; t < 4; ++t) {
                atomicAdd(&out[(size_t)cur_g * 128 + col + 4 * t + 0], acc[t].x);
                atomicAdd(&out[(size_t)cur_g * 128 + col + 4 * t + 1], acc[t].y);
                atomicAdd(&out[(size_t)cur_g * 128 + col + 4 * t + 2], acc[t].z);
                atomicAdd(&out[(size_t)cur_g * 128 + col + 4 * t + 3], acc[t].w);
                acc[t] = make_float4(0, 0, 0, 0);
            }
            cur_g = g;
            #pragma unroll
            for (int t = 0; t < 4; ++t)
                gv[t] = *(const float4*)(g_emb + (size_t)cur_g * 128 + col + 4 * t);
        }
        float d = dot16(nv, gv);
        d += __shfl_xor(d, 1, 64);
        d += __shfl_xor(d, 2, 64);
        d += __shfl_xor(d, 4, 64);
        const float c = 1.0f / (1.0f + __expf(-d));
        #pragma unroll
        for (int t = 0; t < 4; ++t) {
            acc[t].x += c * nv[t].x;
            acc[t].y += c * nv[t].y;
            acc[t].z += c * nv[t].z;
            acc[t].w += c * nv[t].w;
        }
    }

    // final flush
    #pragma unroll
    for (int t = 0; t < 4; ++t) {
        atomicAdd(&out[(size_t)cur_g * 128 + col + 4 * t + 0], acc[t].x);
        atomicAdd(&out[(size_t)cur_g * 128 + col + 4 * t + 1], acc[t].y);
        atomicAdd(&out[(size_t)cur_g * 128 + col + 4 * t + 2], acc[t].z);
        atomicAdd(&out[(size_t)cur_g * 128 + col + 4 * t + 3], acc[t].w);
    }
}

extern "C" void kernel_launch(void* const* d_in, const int* in_sizes, int n_in,
                              void* d_out, int out_size, void* d_ws, size_t ws_size,
                              hipStream_t stream) {
    const float* n_emb   = (const float*)d_in[0];
    const float* g_emb   = (const float*)d_in[1];
    const int*   n_batch = (const int*)d_in[2];
    float* out = (float*)d_out;
    const int N = in_sizes[2];

    hipMemsetAsync(d_out, 0, (size_t)out_size * sizeof(float), stream);

    n2g_attention_kernel<<<GRID_BLOCKS, BLOCK_THREADS, 0, stream>>>(
        n_emb, g_emb, n_batch, out, N);
}

// Round 5
// 355.892 us; speedup vs baseline: 1.7314x; 1.7314x over previous
//
#include <hip/hip_runtime.h>
#include <math.h>

// Node2GraphAttention: out[g] = sum_{i: batch[i]==g} sigmoid(<n_i, g_emb[g]>) * n_i
// N=500000, D=128, G=10000, n_batch sorted ascending.
//
// R5: R3's half-wave (32-lane) float4 layout + 2-stage even/odd software
// pipeline. Per U=8 group: 2 int4 batch loads + 8 float4 n-row loads. The
// loads for group k+1 issue BEFORE group k's compute (loadB/computeA/
// loadA/computeB ping-pong, no register copies -> no R4-style spill).
// R3 was ~50% memory-duty-cycle (burst loads, then ~800 cy compute with
// nothing outstanding); this keeps the memory pipe continuously fed.
// g-row cached in registers per run (sorted batch), atomicAdd flush on
// graph-id change only. 16384 halves x per=32 = 500000 exactly: no tail.

#define BLOCK_THREADS 256
#define GRID_BLOCKS   2048
#define U 8

__device__ __forceinline__ float dot4(float4 a, float4 b) {
    return a.x * b.x + a.y * b.y + a.z * b.z + a.w * b.w;
}

#define FLUSH() do {                                              \
    atomicAdd(&out[(size_t)cur_g * 128 + col + 0], acc.x);        \
    atomicAdd(&out[(size_t)cur_g * 128 + col + 1], acc.y);        \
    atomicAdd(&out[(size_t)cur_g * 128 + col + 2], acc.z);        \
    atomicAdd(&out[(size_t)cur_g * 128 + col + 3], acc.w);        \
    acc = make_float4(0.f, 0.f, 0.f, 0.f);                        \
} while (0)

#define LOAD_GROUP(BASE, B0, B1, NV) do {                         \
    B0 = *(const int4*)(n_batch + (BASE));                        \
    B1 = *(const int4*)(n_batch + (BASE) + 4);                    \
    _Pragma("unroll")                                             \
    for (int j = 0; j < U; ++j)                                   \
        NV[j] = *(const float4*)(n_emb + (size_t)((BASE) + j) * 128 + col); \
} while (0)

#define COMPUTE_GROUP(B0, B1, NV) do {                            \
    if ((B1).w == cur_g) {                                        \
        float d[U];                                               \
        _Pragma("unroll")                                         \
        for (int j = 0; j < U; ++j) d[j] = dot4(NV[j], gv);       \
        _Pragma("unroll")                                         \
        for (int m = 1; m <= 16; m <<= 1) {                       \
            _Pragma("unroll")                                     \
            for (int j = 0; j < U; ++j) d[j] += __shfl_xor(d[j], m, 64); \
        }                                                         \
        _Pragma("unroll")                                         \
        for (int j = 0; j < U; ++j) {                             \
            const float c = 1.0f / (1.0f + __expf(-d[j]));        \
            acc.x += c * NV[j].x; acc.y += c * NV[j].y;           \
            acc.z += c * NV[j].z; acc.w += c * NV[j].w;           \
        }                                                         \
    } else {                                                      \
        const int bb[U] = {(B0).x, (B0).y, (B0).z, (B0).w,        \
                           (B1).x, (B1).y, (B1).z, (B1).w};       \
        _Pragma("unroll")                                         \
        for (int j = 0; j < U; ++j) {                             \
            if (bb[j] != cur_g) {                                 \
                FLUSH();                                          \
                cur_g = bb[j];                                    \
                gv = *(const float4*)(g_emb + (size_t)cur_g * 128 + col); \
            }                                                     \
            float d = dot4(NV[j], gv);                            \
            _Pragma("unroll")                                     \
            for (int m = 1; m <= 16; m <<= 1) d += __shfl_xor(d, m, 64); \
            const float c = 1.0f / (1.0f + __expf(-d));           \
            acc.x += c * NV[j].x; acc.y += c * NV[j].y;           \
            acc.z += c * NV[j].z; acc.w += c * NV[j].w;           \
        }                                                         \
    }                                                             \
} while (0)

__global__ __launch_bounds__(BLOCK_THREADS)
void n2g_attention_kernel(const float* __restrict__ n_emb,
                          const float* __restrict__ g_emb,
                          const int*   __restrict__ n_batch,
                          float* __restrict__ out,
                          int N)
{
    const int hw_id  = blockIdx.x * (BLOCK_THREADS >> 5) + (threadIdx.x >> 5);
    const int l32    = threadIdx.x & 31;
    const int col    = l32 * 4;
    const int num_hw = GRID_BLOCKS * (BLOCK_THREADS >> 5);

    int per = (N + num_hw - 1) / num_hw;
    per = (per + 2 * U - 1) & ~(2 * U - 1);       // multiple of 16
    const int start = hw_id * per;
    if (start >= N) return;
    const int end = min(start + per, N);

    float4 acc = make_float4(0.f, 0.f, 0.f, 0.f);
    int    cur_g = n_batch[start];
    float4 gv = *(const float4*)(g_emb + (size_t)cur_g * 128 + col);

    const int n_full = (end - start) & ~(2 * U - 1);  // pipelined portion
    const int fend   = start + n_full;

    int i = start;
    if (n_full > 0) {
        int4   bA0, bA1, bB0, bB1;
        float4 nvA[U], nvB[U];
        LOAD_GROUP(i, bA0, bA1, nvA);
        for (; i + U < fend; i += 2 * U) {
            LOAD_GROUP(i + U, bB0, bB1, nvB);
            COMPUTE_GROUP(bA0, bA1, nvA);
            if (i + 2 * U < fend) LOAD_GROUP(i + 2 * U, bA0, bA1, nvA);
            COMPUTE_GROUP(bB0, bB1, nvB);
        }
        // n_full is a multiple of 2*U -> loop exits with every group consumed
    }

    // scalar safety tail (empty for N=500000: 16384 halves * 32 = exact)
    for (; i < end; ++i) {
        const int g = n_batch[i];
        const float4 nv = *(const float4*)(n_emb + (size_t)i * 128 + col);
        if (g != cur_g) {
            FLUSH();
            cur_g = g;
            gv = *(const float4*)(g_emb + (size_t)cur_g * 128 + col);
        }
        float d = dot4(nv, gv);
        #pragma unroll
        for (int m = 1; m <= 16; m <<= 1) d += __shfl_xor(d, m, 64);
        const float c = 1.0f / (1.0f + __expf(-d));
        acc.x += c * nv.x;
        acc.y += c * nv.y;
        acc.z += c * nv.z;
        acc.w += c * nv.w;
    }

    // final flush
    atomicAdd(&out[(size_t)cur_g * 128 + col + 0], acc.x);
    atomicAdd(&out[(size_t)cur_g * 128 + col + 1], acc.y);
    atomicAdd(&out[(size_t)cur_g * 128 + col + 2], acc.z);
    atomicAdd(&out[(size_t)cur_g * 128 + col + 3], acc.w);
}

extern "C" void kernel_launch(void* const* d_in, const int* in_sizes, int n_in,
                              void* d_out, int out_size, void* d_ws, size_t ws_size,
                              hipStream_t stream) {
    const float* n_emb   = (const float*)d_in[0];
    const float* g_emb   = (const float*)d_in[1];
    const int*   n_batch = (const int*)d_in[2];
    float* out = (float*)d_out;
    const int N = in_sizes[2];

    hipMemsetAsync(d_out, 0, (size_t)out_size * sizeof(float), stream);

    n2g_attention_kernel<<<GRID_BLOCKS, BLOCK_THREADS, 0, stream>>>(
        n_emb, g_emb, n_batch, out, N);
}